// Round 14
// baseline (39.698 us; speedup 1.0000x reference)
//
#include <hip/hip_runtime.h>
#include <math.h>

// DisCo (distance correlation) for N=8192, scalar output. FOUR dispatches.
// R14 = R13 structure EXACTLY (39.5us best) + packed-fp32 experiment:
// inner loops rewritten on clang ext_vector float2 so hipcc can emit VOP3P
// v_pk_sub/v_pk_max/v_pk_fma_f32 (2 elements/instr). abs has no VOP3P
// modifier -> |t| = pk_max(t, -t) (neg IS a free VOP3P modifier).
// Algebra (validated R11/R13, absmax 0.0):
//   r_i = avga_i - ha (ha = ga/2);  d' = |a_i-a_j| - r_j,  e' = |b_i-b_j| - s_j
//   Q'_i = sum_j w_j d' e';  T_AB_i = Q'_i - s_i(P0a_i-Swr) - r_i(P0b_i-Sws)
//          + r_i s_i W;  S_AA closed-form from moments.
//   K1 k_pass1 (512x4): partial row sums pa,pb + dbl gpa/gpb[2048].
//   K2 k_mid   (32):    ha/hb; rr/ss arrays; 9 moment partials scal[9][32].
//   K3 k_pass2 (2048):  full-row Q' + in-block T_AB -> fAB[2048].
//   K4 k_fin   (1x256): reduce fAB + scal; closed-form dens; power; clamp.
// No atomics/fences (R4). Fixed-order reductions -> deterministic.

#define NN 8192
#define BLK 256
#define RPT 4
#define ROWS_PER_BLOCK 16
#define GRIDX 512
#define CSPLIT 4
#define SEGC 2048
#define ITERS 8
#define NBLK (GRIDX * CSPLIT)
#define MIDB 32
#define G2BLK 2048
#define INV_N (1.0f / NN)
#define NSC 9   // 0:W 1:Ma1 2:Ma2 3:Mb1 4:Mb2 5:Swr 6:Sws 7:Swr2 8:Sws2

typedef float f2 __attribute__((ext_vector_type(2)));
typedef float f4 __attribute__((ext_vector_type(4)));

__device__ __forceinline__ f2 vabs2(f2 x) {
  return __builtin_elementwise_max(x, -x);   // v_pk_max_f32 with neg modifier
}

// ---------------------------------------------------------------- K1: pass 1
__global__ __launch_bounds__(BLK) void k_pass1(
    const float* __restrict__ a, const float* __restrict__ b,
    const float* __restrict__ w,
    float* __restrict__ pa, float* __restrict__ pb,
    double* __restrict__ gpa, double* __restrict__ gpb) {
  const int lane = threadIdx.x & 63;
  const int wv = threadIdx.x >> 6;
  const int i0 = blockIdx.x * ROWS_PER_BLOCK + wv * RPT;
  const int seg = blockIdx.y;

  float ai[RPT], bi[RPT];
  f2 sa2[RPT], sb2[RPT];
#pragma unroll
  for (int m = 0; m < RPT; ++m) {
    ai[m] = a[i0 + m]; bi[m] = b[i0 + m];
    sa2[m] = (f2)0.f; sb2[m] = (f2)0.f;
  }

  const int jb = seg * SEGC;
  const f4* a4 = (const f4*)(a + jb) + lane;
  const f4* b4 = (const f4*)(b + jb) + lane;
  const f4* w4 = (const f4*)(w + jb) + lane;

  f4 A0 = a4[0], B0 = b4[0], W0 = w4[0];
#pragma unroll 1
  for (int k = 0; k < ITERS - 1; ++k) {
    const int nx = (k + 1) * 64;
    const f4 A1 = a4[nx], B1 = b4[nx], W1 = w4[nx];
#define P1H(H)                                                            \
    {                                                                     \
      const f2 Ah = A0.H, Bh = B0.H, Wh = W0.H;                           \
      _Pragma("unroll")                                                   \
      for (int m = 0; m < RPT; ++m) {                                     \
        sa2[m] = __builtin_elementwise_fma(vabs2(ai[m] - Ah), Wh, sa2[m]);\
        sb2[m] = __builtin_elementwise_fma(vabs2(bi[m] - Bh), Wh, sb2[m]);\
      }                                                                   \
    }
    P1H(lo) P1H(hi)
    A0 = A1; B0 = B1; W0 = W1;
  }
  P1H(lo) P1H(hi)
#undef P1H

  float sa[RPT], sb[RPT];
#pragma unroll
  for (int m = 0; m < RPT; ++m) {
    sa[m] = sa2[m].x + sa2[m].y;
    sb[m] = sb2[m].x + sb2[m].y;
  }
#pragma unroll
  for (int off = 32; off >= 1; off >>= 1) {
#pragma unroll
    for (int m = 0; m < RPT; ++m) {
      sa[m] += __shfl_xor(sa[m], off);
      sb[m] += __shfl_xor(sb[m], off);
    }
  }

  __shared__ double gla[4], glb[4];
  if (lane == 0) {
#pragma unroll
    for (int m = 0; m < RPT; ++m) {
      pa[seg * NN + i0 + m] = sa[m];
      pb[seg * NN + i0 + m] = sb[m];
    }
    double da = 0.0, db = 0.0;
#pragma unroll
    for (int m = 0; m < RPT; ++m) {
      const double wi = (double)w[i0 + m];
      da += (double)sa[m] * wi;
      db += (double)sb[m] * wi;
    }
    gla[wv] = da; glb[wv] = db;
  }
  __syncthreads();
  if (threadIdx.x == 0) {
    const int bid = blockIdx.y * GRIDX + blockIdx.x;
    gpa[bid] = gla[0] + gla[1] + gla[2] + gla[3];
    gpb[bid] = glb[0] + glb[1] + glb[2] + glb[3];
  }
}

// ---------------- K2: ha/hb; rr/ss arrays; 9 moment partials; hs[2] scalars
__global__ __launch_bounds__(BLK) void k_mid(
    const float* __restrict__ a, const float* __restrict__ b,
    const float* __restrict__ w,
    const float* __restrict__ pa, const float* __restrict__ pb,
    const double* __restrict__ gpa, const double* __restrict__ gpb,
    float* __restrict__ rr, float* __restrict__ ss,
    double* __restrict__ scal, double* __restrict__ hs) {
  const int lane = threadIdx.x & 63;
  const int wv = threadIdx.x >> 6;

  __shared__ double gsum[2];
  if (wv < 2) {
    const double* g = wv ? gpb : gpa;
    double s = 0.0;
    for (int k = 0; k < NBLK / 64; ++k) s += g[lane + 64 * k];
#pragma unroll
    for (int off = 32; off >= 1; off >>= 1) s += __shfl_xor(s, off);
    if (lane == 0) gsum[wv] = s;
  }
  __syncthreads();
  const double n2 = (double)NN * (double)NN;
  const float ha = (float)(0.5 * gsum[0] / n2);
  const float hb = (float)(0.5 * gsum[1] / n2);
  if (blockIdx.x == 0 && threadIdx.x == 0) { hs[0] = (double)ha; hs[1] = (double)hb; }

  const int i = blockIdx.x * BLK + threadIdx.x;
  const float av = (pa[i] + pa[NN + i] + pa[2 * NN + i] + pa[3 * NN + i]) * INV_N;
  const float bv = (pb[i] + pb[NN + i] + pb[2 * NN + i] + pb[3 * NN + i]) * INV_N;
  const float ri = av - ha;
  const float si = bv - hb;
  const float wi = w[i], aiv = a[i], biv = b[i];
  rr[i] = ri;  ss[i] = si;

  double p[NSC];
  p[0] = (double)wi;
  p[1] = (double)wi * aiv;
  p[2] = (double)wi * aiv * aiv;
  p[3] = (double)wi * biv;
  p[4] = (double)wi * biv * biv;
  p[5] = (double)wi * ri;
  p[6] = (double)wi * si;
  p[7] = (double)wi * ri * ri;
  p[8] = (double)wi * si * si;
#pragma unroll
  for (int off = 32; off >= 1; off >>= 1) {
#pragma unroll
    for (int t = 0; t < NSC; ++t) p[t] += __shfl_xor(p[t], off);
  }
  __shared__ double lp[NSC][4];
  if (lane == 0) {
#pragma unroll
    for (int t = 0; t < NSC; ++t) lp[t][wv] = p[t];
  }
  __syncthreads();
  if (threadIdx.x == 0) {
#pragma unroll
    for (int t = 0; t < NSC; ++t)
      scal[t * MIDB + blockIdx.x] = lp[t][0] + lp[t][1] + lp[t][2] + lp[t][3];
  }
}

// ---- K3: pass 2 — full rows per block; packed Q' sweep + in-block T_AB
__global__ __launch_bounds__(BLK) void k_pass2(
    const float* __restrict__ a, const float* __restrict__ b,
    const float* __restrict__ w,
    const float* __restrict__ rr, const float* __restrict__ ss,
    const double* __restrict__ scal, const double* __restrict__ hs,
    double* __restrict__ fAB) {
  const int lane = threadIdx.x & 63;
  const int wv = threadIdx.x >> 6;
  const int i0 = blockIdx.x * RPT;            // 4 complete rows per block

  // wave prologue: W, Swr, Sws from k_mid's 32 partials (broadcast loads)
  double Wd   = scal[0 * MIDB + (lane & 31)];
  double Swrd = scal[5 * MIDB + (lane & 31)];
  double Swsd = scal[6 * MIDB + (lane & 31)];
#pragma unroll
  for (int off = 16; off >= 1; off >>= 1) {
    Wd   += __shfl_xor(Wd, off);
    Swrd += __shfl_xor(Swrd, off);
    Swsd += __shfl_xor(Swsd, off);
  }

  float ai[RPT], bi[RPT];
  f2 q2[RPT];
#pragma unroll
  for (int m = 0; m < RPT; ++m) {
    ai[m] = a[i0 + m]; bi[m] = b[i0 + m];
    q2[m] = (f2)0.f;
  }

  const int jb = wv * SEGC;                   // wave -> column segment
  const f4* a4 = (const f4*)(a + jb)  + lane;
  const f4* b4 = (const f4*)(b + jb)  + lane;
  const f4* w4 = (const f4*)(w + jb)  + lane;
  const f4* r4 = (const f4*)(rr + jb) + lane;
  const f4* s4 = (const f4*)(ss + jb) + lane;

#pragma unroll 1
  for (int k = 0; k < ITERS; ++k) {
    const int ix = k * 64;
    const f4 A = a4[ix], B = b4[ix], Wt = w4[ix], R = r4[ix], S = s4[ix];
#define P2H(H)                                                        \
    {                                                                 \
      const f2 Ah = A.H, Bh = B.H, Wh = Wt.H, Rh = R.H, Sh = S.H;     \
      _Pragma("unroll")                                               \
      for (int m = 0; m < RPT; ++m) {                                 \
        const f2 dp = vabs2(ai[m] - Ah) - Rh;                         \
        const f2 ep = vabs2(bi[m] - Bh) - Sh;                         \
        q2[m] = __builtin_elementwise_fma(Wh * dp, ep, q2[m]);        \
      }                                                               \
    }
    P2H(lo) P2H(hi)
#undef P2H
  }

  float q[RPT];
#pragma unroll
  for (int m = 0; m < RPT; ++m) q[m] = q2[m].x + q2[m].y;
#pragma unroll
  for (int off = 32; off >= 1; off >>= 1) {
#pragma unroll
    for (int m = 0; m < RPT; ++m) q[m] += __shfl_xor(q[m], off);
  }

  __shared__ float lq[CSPLIT][RPT];
  __shared__ double lab[RPT];
  if (lane == 0) {
#pragma unroll
    for (int m = 0; m < RPT; ++m) lq[wv][m] = q[m];
  }
  __syncthreads();
  if (threadIdx.x < RPT) {                    // lanes 0-3 of wave 0 hold Wd etc.
    const int m = threadIdx.x;
    const double Qi = (double)lq[0][m] + lq[1][m] + lq[2][m] + lq[3][m];
    const double ha = hs[0], hb = hs[1];
    const double ri = (double)rr[i0 + m];
    const double si = (double)ss[i0 + m];
    const double wi = (double)w[i0 + m];
    const double P0a = (ri + ha) * (double)NN;   // N * avga_i
    const double P0b = (si + hb) * (double)NN;
    const double TAB = Qi - si * (P0a - Swrd) - ri * (P0b - Swsd) + ri * si * Wd;
    lab[m] = fabs(TAB) * wi;
  }
  __syncthreads();
  if (threadIdx.x == 0)
    fAB[blockIdx.x] = lab[0] + lab[1] + lab[2] + lab[3];
}

// ---------- K4: finalize — reduce fAB[2048]+scal; closed-form dens; power
__global__ __launch_bounds__(BLK) void k_fin(
    const double* __restrict__ fAB, const double* __restrict__ scal,
    const double* __restrict__ hs, const int* __restrict__ powerPtr,
    float* __restrict__ out) {
  const int lane = threadIdx.x & 63;
  const int wv = threadIdx.x >> 6;

  double ab = 0.0;
#pragma unroll
  for (int k = 0; k < G2BLK / BLK; ++k) ab += fAB[threadIdx.x + k * BLK];
#pragma unroll
  for (int off = 32; off >= 1; off >>= 1) ab += __shfl_xor(ab, off);
  __shared__ double l[4];
  __shared__ double sc[NSC];
  if (lane == 0) l[wv] = ab;
  if (threadIdx.x < NSC) {
    double s = 0.0;
    for (int k = 0; k < MIDB; ++k) s += scal[threadIdx.x * MIDB + k];
    sc[threadIdx.x] = s;
  }
  __syncthreads();

  if (threadIdx.x == 0) {
    const double n2 = (double)NN * (double)NN;
    const double sab = l[0] + l[1] + l[2] + l[3];
    const double W = sc[0], Ma1 = sc[1], Ma2 = sc[2], Mb1 = sc[3], Mb2 = sc[4];
    const double Swr = sc[5], Sws = sc[6], Swr2 = sc[7], Sws2 = sc[8];
    const double ha = hs[0], hb = hs[1];

    const double S_AA = 2.0 * W * Ma2 - 2.0 * Ma1 * Ma1
                      - 4.0 * (double)NN * (Swr2 + ha * Swr)
                      + 2.0 * W * Swr2 + 2.0 * Swr * Swr;
    const double S_BB = 2.0 * W * Mb2 - 2.0 * Mb1 * Mb1
                      - 4.0 * (double)NN * (Sws2 + hb * Sws)
                      + 2.0 * W * Sws2 + 2.0 * Sws * Sws;

    const double num = sab / n2;
    const double mAA = S_AA / n2;
    const double mBB = S_BB / n2;
    const double den = fabs(mAA * mBB);
    const int p = powerPtr[0];
    double d;
    if (p == 1) {
      d = num / sqrt(den + 1e-12);
    } else if (p == 2) {
      d = (num * num) / (den + 1e-12);
    } else {
      d = pow(num / sqrt(mAA * mBB) + 1e-12, (double)p);
    }
    if (isnan(d)) d = 0.0;
    if (d < 0.0) d = 0.0;
    out[0] = (float)d;
  }
}

// -------------------------------------------------------------------- launcher
extern "C" void kernel_launch(void* const* d_in, const int* in_sizes, int n_in,
                              void* d_out, int out_size, void* d_ws, size_t ws_size,
                              hipStream_t stream) {
  const float* a = (const float*)d_in[0];
  const float* b = (const float*)d_in[1];
  const float* w = (const float*)d_in[2];
  const int* power = (const int*)d_in[3];
  float* out = (float*)d_out;

  double* dws = (double*)d_ws;           // 8B-aligned base
  double* gpa  = dws;                    // [2048]
  double* gpb  = gpa + NBLK;             // [2048]
  double* scal = gpb + NBLK;             // [9*32]
  double* hs   = scal + NSC * MIDB;      // [2]
  double* fAB  = hs + 2;                 // [2048]
  float* fp    = (float*)(fAB + G2BLK);
  float* pa    = fp;                     // [4N]
  float* pb    = pa + 4 * NN;            // [4N]
  float* rr    = pb + 4 * NN;            // [N]
  float* ss    = rr + NN;                // [N]

  const dim3 grid(GRIDX, CSPLIT);
  k_pass1<<<grid, BLK, 0, stream>>>(a, b, w, pa, pb, gpa, gpb);
  k_mid<<<MIDB, BLK, 0, stream>>>(a, b, w, pa, pb, gpa, gpb, rr, ss, scal, hs);
  k_pass2<<<G2BLK, BLK, 0, stream>>>(a, b, w, rr, ss, scal, hs, fAB);
  k_fin<<<1, BLK, 0, stream>>>(fAB, scal, hs, power, out);
}

// Round 15
// 36.417 us; speedup vs baseline: 1.0901x; 1.0901x over previous
//
#include <hip/hip_runtime.h>
#include <math.h>

// DisCo (distance correlation) for N=8192, scalar output. FOUR dispatches.
// R15 = R13 structure + two pass2 cuts:
//  (1) 5 VALU/pair (was 6): wdp = fma(w_j, |ai-aj|, -wr_j) with precomputed
//      wr_j = w_j*r_j (neg/abs are free VOP3 input modifiers).
//  (2) RPT=8 rows/block, 1024 blocks (was 4/2048): halves pass2's L2 read
//      traffic (each block streams the full arrays once) and doubles VALU
//      per loaded byte. 4096 waves = 4/SIMD; 8 indep FMA chains/lane for ILP.
// Algebra (validated R11/R13, absmax 0.0):
//   r_i = avga_i - ha (ha = ga/2);  d' = |a_i-a_j| - r_j,  e' = |b_i-b_j| - s_j
//   Q'_i = sum_j w_j d' e';  T_AB_i = Q'_i - s_i(P0a_i-Swr) - r_i(P0b_i-Sws)
//          + r_i s_i W;  S_AA/S_BB closed-form from moments.
//   K1 k_pass1 (512x4): partial row sums pa,pb + dbl gpa/gpb[2048].
//   K2 k_mid   (32):    ha/hb; rr/ss/wr arrays; 9 moment partials scal[9][32].
//   K3 k_pass2 (1024):  8 full rows/block; 5-op Q' sweep; in-block T_AB
//                       -> fAB[1024] (double).
//   K4 k_fin   (1x256): reduce fAB + scal; closed-form dens; power; clamp.
// No atomics/fences (R4). Fixed-order reductions -> deterministic.
// Lessons ledger: R4 no per-block fences; R6 VGPR cliff; R9 epilogue<<main,
// 1-block reads <<100KB; R10 no redundant per-block O(N) rebuilds; R12 serial
// merge loses to gap; R14 packed-f32 neutral on CDNA4.

#define NN 8192
#define BLK 256
#define RPT 4
#define ROWS_PER_BLOCK 16
#define GRIDX 512
#define CSPLIT 4
#define SEGC 2048
#define ITERS 8
#define NBLK (GRIDX * CSPLIT)
#define MIDB 32
#define RPT2 8                    // pass2 rows per block
#define G2BLK (NN / RPT2)         // 1024 pass2 blocks
#define INV_N (1.0f / NN)
#define NSC 9   // 0:W 1:Ma1 2:Ma2 3:Mb1 4:Mb2 5:Swr 6:Sws 7:Swr2 8:Sws2

// ---------------------------------------------------------------- K1: pass 1
__device__ __forceinline__ void p1_elem(
    float aj, float bj, float wj,
    const float* __restrict__ ai, const float* __restrict__ bi,
    float* __restrict__ sa, float* __restrict__ sb) {
#pragma unroll
  for (int m = 0; m < RPT; ++m) {
    sa[m] = fmaf(fabsf(ai[m] - aj), wj, sa[m]);
    sb[m] = fmaf(fabsf(bi[m] - bj), wj, sb[m]);
  }
}

__global__ __launch_bounds__(BLK) void k_pass1(
    const float* __restrict__ a, const float* __restrict__ b,
    const float* __restrict__ w,
    float* __restrict__ pa, float* __restrict__ pb,
    double* __restrict__ gpa, double* __restrict__ gpb) {
  const int lane = threadIdx.x & 63;
  const int wv = threadIdx.x >> 6;
  const int i0 = blockIdx.x * ROWS_PER_BLOCK + wv * RPT;
  const int seg = blockIdx.y;

  float ai[RPT], bi[RPT], sa[RPT], sb[RPT];
#pragma unroll
  for (int m = 0; m < RPT; ++m) {
    ai[m] = a[i0 + m]; bi[m] = b[i0 + m];
    sa[m] = 0.f; sb[m] = 0.f;
  }

  const int jb = seg * SEGC;
  const float4* a4 = (const float4*)(a + jb) + lane;
  const float4* b4 = (const float4*)(b + jb) + lane;
  const float4* w4 = (const float4*)(w + jb) + lane;

  float4 A0 = a4[0], B0 = b4[0], W0 = w4[0];
#pragma unroll 1
  for (int k = 0; k < ITERS - 1; ++k) {
    const int nx = (k + 1) * 64;
    const float4 A1 = a4[nx], B1 = b4[nx], W1 = w4[nx];
    p1_elem(A0.x, B0.x, W0.x, ai, bi, sa, sb);
    p1_elem(A0.y, B0.y, W0.y, ai, bi, sa, sb);
    p1_elem(A0.z, B0.z, W0.z, ai, bi, sa, sb);
    p1_elem(A0.w, B0.w, W0.w, ai, bi, sa, sb);
    A0 = A1; B0 = B1; W0 = W1;
  }
  p1_elem(A0.x, B0.x, W0.x, ai, bi, sa, sb);
  p1_elem(A0.y, B0.y, W0.y, ai, bi, sa, sb);
  p1_elem(A0.z, B0.z, W0.z, ai, bi, sa, sb);
  p1_elem(A0.w, B0.w, W0.w, ai, bi, sa, sb);

#pragma unroll
  for (int off = 32; off >= 1; off >>= 1) {
#pragma unroll
    for (int m = 0; m < RPT; ++m) {
      sa[m] += __shfl_xor(sa[m], off);
      sb[m] += __shfl_xor(sb[m], off);
    }
  }

  __shared__ double gla[4], glb[4];
  if (lane == 0) {
#pragma unroll
    for (int m = 0; m < RPT; ++m) {
      pa[seg * NN + i0 + m] = sa[m];
      pb[seg * NN + i0 + m] = sb[m];
    }
    double da = 0.0, db = 0.0;
#pragma unroll
    for (int m = 0; m < RPT; ++m) {
      const double wi = (double)w[i0 + m];
      da += (double)sa[m] * wi;
      db += (double)sb[m] * wi;
    }
    gla[wv] = da; glb[wv] = db;
  }
  __syncthreads();
  if (threadIdx.x == 0) {
    const int bid = blockIdx.y * GRIDX + blockIdx.x;
    gpa[bid] = gla[0] + gla[1] + gla[2] + gla[3];
    gpb[bid] = glb[0] + glb[1] + glb[2] + glb[3];
  }
}

// ------------- K2: ha/hb; rr/ss/wr arrays; 9 moment partials; hs[2] scalars
__global__ __launch_bounds__(BLK) void k_mid(
    const float* __restrict__ a, const float* __restrict__ b,
    const float* __restrict__ w,
    const float* __restrict__ pa, const float* __restrict__ pb,
    const double* __restrict__ gpa, const double* __restrict__ gpb,
    float* __restrict__ rr, float* __restrict__ ss, float* __restrict__ wrv,
    double* __restrict__ scal, double* __restrict__ hs) {
  const int lane = threadIdx.x & 63;
  const int wv = threadIdx.x >> 6;

  __shared__ double gsum[2];
  if (wv < 2) {
    const double* g = wv ? gpb : gpa;
    double s = 0.0;
    for (int k = 0; k < NBLK / 64; ++k) s += g[lane + 64 * k];
#pragma unroll
    for (int off = 32; off >= 1; off >>= 1) s += __shfl_xor(s, off);
    if (lane == 0) gsum[wv] = s;
  }
  __syncthreads();
  const double n2 = (double)NN * (double)NN;
  const float ha = (float)(0.5 * gsum[0] / n2);
  const float hb = (float)(0.5 * gsum[1] / n2);
  if (blockIdx.x == 0 && threadIdx.x == 0) { hs[0] = (double)ha; hs[1] = (double)hb; }

  const int i = blockIdx.x * BLK + threadIdx.x;
  const float av = (pa[i] + pa[NN + i] + pa[2 * NN + i] + pa[3 * NN + i]) * INV_N;
  const float bv = (pb[i] + pb[NN + i] + pb[2 * NN + i] + pb[3 * NN + i]) * INV_N;
  const float ri = av - ha;
  const float si = bv - hb;
  const float wi = w[i], aiv = a[i], biv = b[i];
  rr[i] = ri;  ss[i] = si;  wrv[i] = wi * ri;

  double p[NSC];
  p[0] = (double)wi;
  p[1] = (double)wi * aiv;
  p[2] = (double)wi * aiv * aiv;
  p[3] = (double)wi * biv;
  p[4] = (double)wi * biv * biv;
  p[5] = (double)wi * ri;
  p[6] = (double)wi * si;
  p[7] = (double)wi * ri * ri;
  p[8] = (double)wi * si * si;
#pragma unroll
  for (int off = 32; off >= 1; off >>= 1) {
#pragma unroll
    for (int t = 0; t < NSC; ++t) p[t] += __shfl_xor(p[t], off);
  }
  __shared__ double lp[NSC][4];
  if (lane == 0) {
#pragma unroll
    for (int t = 0; t < NSC; ++t) lp[t][wv] = p[t];
  }
  __syncthreads();
  if (threadIdx.x == 0) {
#pragma unroll
    for (int t = 0; t < NSC; ++t)
      scal[t * MIDB + blockIdx.x] = lp[t][0] + lp[t][1] + lp[t][2] + lp[t][3];
  }
}

// ---- K3: pass 2 — 8 full rows/block; 5-op Q' sweep; in-block T_AB finish
__global__ __launch_bounds__(BLK) void k_pass2(
    const float* __restrict__ a, const float* __restrict__ b,
    const float* __restrict__ w,
    const float* __restrict__ rr, const float* __restrict__ ss,
    const float* __restrict__ wrv,
    const double* __restrict__ scal, const double* __restrict__ hs,
    double* __restrict__ fAB) {
  const int lane = threadIdx.x & 63;
  const int wv = threadIdx.x >> 6;
  const int i0 = blockIdx.x * RPT2;           // 8 complete rows per block

  // wave prologue: W, Swr, Sws from k_mid's 32 partials (broadcast loads)
  double Wd   = scal[0 * MIDB + (lane & 31)];
  double Swrd = scal[5 * MIDB + (lane & 31)];
  double Swsd = scal[6 * MIDB + (lane & 31)];
#pragma unroll
  for (int off = 16; off >= 1; off >>= 1) {
    Wd   += __shfl_xor(Wd, off);
    Swrd += __shfl_xor(Swrd, off);
    Swsd += __shfl_xor(Swsd, off);
  }

  float ai[RPT2], bi[RPT2], q[RPT2];
#pragma unroll
  for (int m = 0; m < RPT2; ++m) {
    ai[m] = a[i0 + m]; bi[m] = b[i0 + m];
    q[m] = 0.f;
  }

  const int jb = wv * SEGC;                   // wave -> column segment
  const float4* a4 = (const float4*)(a + jb)   + lane;
  const float4* b4 = (const float4*)(b + jb)   + lane;
  const float4* w4 = (const float4*)(w + jb)   + lane;
  const float4* r4 = (const float4*)(wrv + jb) + lane;   // wr stream
  const float4* s4 = (const float4*)(ss + jb)  + lane;

#pragma unroll 1
  for (int k = 0; k < ITERS; ++k) {
    const int ix = k * 64;
    const float4 A = a4[ix], B = b4[ix], Wt = w4[ix], R = r4[ix], S = s4[ix];
#define P2E(e)                                                  \
    {                                                           \
      _Pragma("unroll")                                         \
      for (int m = 0; m < RPT2; ++m) {                          \
        const float ta = ai[m] - A.e;                           \
        const float tb = bi[m] - B.e;                           \
        const float wdp = fmaf(Wt.e, fabsf(ta), -R.e);          \
        const float ep = fabsf(tb) - S.e;                       \
        q[m] = fmaf(wdp, ep, q[m]);                             \
      }                                                         \
    }
    P2E(x) P2E(y) P2E(z) P2E(w)
#undef P2E
  }

#pragma unroll
  for (int off = 32; off >= 1; off >>= 1) {
#pragma unroll
    for (int m = 0; m < RPT2; ++m) q[m] += __shfl_xor(q[m], off);
  }

  __shared__ float lq[CSPLIT][RPT2];
  __shared__ double lab[RPT2];
  if (lane == 0) {
#pragma unroll
    for (int m = 0; m < RPT2; ++m) lq[wv][m] = q[m];
  }
  __syncthreads();
  if (threadIdx.x < RPT2) {                   // lanes 0-7 of wave 0 hold Wd etc.
    const int m = threadIdx.x;
    const double Qi = (double)lq[0][m] + lq[1][m] + lq[2][m] + lq[3][m];
    const double ha = hs[0], hb = hs[1];
    const double ri = (double)rr[i0 + m];
    const double si = (double)ss[i0 + m];
    const double wi = (double)w[i0 + m];
    const double P0a = (ri + ha) * (double)NN;   // N * avga_i
    const double P0b = (si + hb) * (double)NN;
    const double TAB = Qi - si * (P0a - Swrd) - ri * (P0b - Swsd) + ri * si * Wd;
    lab[m] = fabs(TAB) * wi;
  }
  __syncthreads();
  if (threadIdx.x == 0) {
    double s = 0.0;
#pragma unroll
    for (int m = 0; m < RPT2; ++m) s += lab[m];
    fAB[blockIdx.x] = s;
  }
}

// ---------- K4: finalize — reduce fAB[1024]+scal; closed-form dens; power
__global__ __launch_bounds__(BLK) void k_fin(
    const double* __restrict__ fAB, const double* __restrict__ scal,
    const double* __restrict__ hs, const int* __restrict__ powerPtr,
    float* __restrict__ out) {
  const int lane = threadIdx.x & 63;
  const int wv = threadIdx.x >> 6;

  double ab = 0.0;
#pragma unroll
  for (int k = 0; k < G2BLK / BLK; ++k) ab += fAB[threadIdx.x + k * BLK];
#pragma unroll
  for (int off = 32; off >= 1; off >>= 1) ab += __shfl_xor(ab, off);
  __shared__ double l[4];
  __shared__ double sc[NSC];
  if (lane == 0) l[wv] = ab;
  if (threadIdx.x < NSC) {
    double s = 0.0;
    for (int k = 0; k < MIDB; ++k) s += scal[threadIdx.x * MIDB + k];
    sc[threadIdx.x] = s;
  }
  __syncthreads();

  if (threadIdx.x == 0) {
    const double n2 = (double)NN * (double)NN;
    const double sab = l[0] + l[1] + l[2] + l[3];
    const double W = sc[0], Ma1 = sc[1], Ma2 = sc[2], Mb1 = sc[3], Mb2 = sc[4];
    const double Swr = sc[5], Sws = sc[6], Swr2 = sc[7], Sws2 = sc[8];
    const double ha = hs[0], hb = hs[1];

    const double S_AA = 2.0 * W * Ma2 - 2.0 * Ma1 * Ma1
                      - 4.0 * (double)NN * (Swr2 + ha * Swr)
                      + 2.0 * W * Swr2 + 2.0 * Swr * Swr;
    const double S_BB = 2.0 * W * Mb2 - 2.0 * Mb1 * Mb1
                      - 4.0 * (double)NN * (Sws2 + hb * Sws)
                      + 2.0 * W * Sws2 + 2.0 * Sws * Sws;

    const double num = sab / n2;
    const double mAA = S_AA / n2;
    const double mBB = S_BB / n2;
    const double den = fabs(mAA * mBB);
    const int p = powerPtr[0];
    double d;
    if (p == 1) {
      d = num / sqrt(den + 1e-12);
    } else if (p == 2) {
      d = (num * num) / (den + 1e-12);
    } else {
      d = pow(num / sqrt(mAA * mBB) + 1e-12, (double)p);
    }
    if (isnan(d)) d = 0.0;
    if (d < 0.0) d = 0.0;
    out[0] = (float)d;
  }
}

// -------------------------------------------------------------------- launcher
extern "C" void kernel_launch(void* const* d_in, const int* in_sizes, int n_in,
                              void* d_out, int out_size, void* d_ws, size_t ws_size,
                              hipStream_t stream) {
  const float* a = (const float*)d_in[0];
  const float* b = (const float*)d_in[1];
  const float* w = (const float*)d_in[2];
  const int* power = (const int*)d_in[3];
  float* out = (float*)d_out;

  double* dws = (double*)d_ws;           // 8B-aligned base
  double* gpa  = dws;                    // [2048]
  double* gpb  = gpa + NBLK;             // [2048]
  double* scal = gpb + NBLK;             // [9*32]
  double* hs   = scal + NSC * MIDB;      // [2]
  double* fAB  = hs + 2;                 // [1024]
  float* fp    = (float*)(fAB + G2BLK);
  float* pa    = fp;                     // [4N]
  float* pb    = pa + 4 * NN;            // [4N]
  float* rr    = pb + 4 * NN;            // [N]
  float* ss    = rr + NN;                // [N]
  float* wrv   = ss + NN;                // [N]

  const dim3 grid(GRIDX, CSPLIT);
  k_pass1<<<grid, BLK, 0, stream>>>(a, b, w, pa, pb, gpa, gpb);
  k_mid<<<MIDB, BLK, 0, stream>>>(a, b, w, pa, pb, gpa, gpb, rr, ss, wrv, scal, hs);
  k_pass2<<<G2BLK, BLK, 0, stream>>>(a, b, w, rr, ss, wrv, scal, hs, fAB);
  k_fin<<<1, BLK, 0, stream>>>(fAB, scal, hs, power, out);
}

// Round 16
// 36.254 us; speedup vs baseline: 1.0950x; 1.0045x over previous
//
#include <hip/hip_runtime.h>
#include <math.h>

// DisCo (distance correlation) for N=8192, scalar output. THREE dispatches.
// R16: k_mid eliminated via ha-free moments. Identity: ga = N*Sua1 where
// Sua1 = sum_i w_i*avga_i, so ha = Sua1/(2N), and Swr = Sua1 - ha*W,
// Swr2 = Sua2 - 2ha*Sua1 + ha^2*W (all from 9 ha-free moments that pass1
// emits per-block: W,Ma1,Ma2,Mb1,Mb2,Sua1,Sua2,Sub1,Sub2).
//   K1 k_pass1 (1024): 8 FULL rows/block; 4 waves x 2048-col segments; LDS
//       combine -> writes avga/avgb directly + 9 dbl moment partials [1024].
//   K2 k_pass2 (1024): prologue reduces W/Sua1/Sub1 -> ha,hb,Swr,Sws; 5-op
//       Q' sweep with on-the-fly wr_j,s_j (+3 ops per j-elem, amortized over
//       8 rows); in-block T_AB -> fAB[1024].
//   K3 k_fin   (1x256): reduce fAB + 9 moments (80KB, <<100KB rule);
//       closed-form S_AA/S_BB; power branch; NaN/clamp.
// Algebra (validated R11/R13/R15, absmax 0.0):
//   r_i = avga_i - ha; d' = |a_i-a_j| - r_j; e' = |b_i-b_j| - s_j
//   Q'_i = sum_j w_j d' e'  (5 VALU/pair: wdp = fma(w_j,|ta|,-wr_j))
//   T_AB_i = Q'_i - s_i(P0a_i-Swr) - r_i(P0b_i-Sws) + r_i s_i W
//   S_AA = 2W*Ma2 - 2Ma1^2 - 4N(Swr2 + ha*Swr) + 2W*Swr2 + 2Swr^2
// No atomics/fences (R4). Fixed-order reductions -> deterministic.
// Ledger: R4 no per-block fences; R6 VGPR cliff; R9 epilogue<<main, 1-block
// reads <<100KB; R10 no redundant per-block O(N) rebuilds; R12 serial merge
// loses to gap; R14 packed-f32 neutral; R15 ILP-for-TLP @ RPT=8 wins.

#define NN 8192
#define BLK 256
#define NW 4                      // waves per block
#define RP 8                      // rows per block (both passes)
#define GBLK (NN / RP)            // 1024 blocks
#define SEGC (NN / NW)            // 2048 cols per wave
#define ITERS (SEGC / 256)        // 8 float4-iters per wave
#define NSC 9   // 0:W 1:Ma1 2:Ma2 3:Mb1 4:Mb2 5:Sua1 6:Sua2 7:Sub1 8:Sub2

// ------------------------- K1: pass 1 — full rows, avg + ha-free moments
__global__ __launch_bounds__(BLK) void k_pass1(
    const float* __restrict__ a, const float* __restrict__ b,
    const float* __restrict__ w,
    float* __restrict__ avga, float* __restrict__ avgb,
    double* __restrict__ gmom) {
  const int lane = threadIdx.x & 63;
  const int wv = threadIdx.x >> 6;
  const int i0 = blockIdx.x * RP;

  float ai[RP], bi[RP], sa[RP], sb[RP];
#pragma unroll
  for (int m = 0; m < RP; ++m) {
    ai[m] = a[i0 + m]; bi[m] = b[i0 + m];
    sa[m] = 0.f; sb[m] = 0.f;
  }

  const int jb = wv * SEGC;
  const float4* a4 = (const float4*)(a + jb) + lane;
  const float4* b4 = (const float4*)(b + jb) + lane;
  const float4* w4 = (const float4*)(w + jb) + lane;

#pragma unroll 1
  for (int k = 0; k < ITERS; ++k) {
    const int ix = k * 64;
    const float4 A = a4[ix], B = b4[ix], Wt = w4[ix];
#define P1E(e)                                              \
    {                                                       \
      _Pragma("unroll")                                     \
      for (int m = 0; m < RP; ++m) {                        \
        sa[m] = fmaf(fabsf(ai[m] - A.e), Wt.e, sa[m]);      \
        sb[m] = fmaf(fabsf(bi[m] - B.e), Wt.e, sb[m]);      \
      }                                                     \
    }
    P1E(x) P1E(y) P1E(z) P1E(w)
#undef P1E
  }

#pragma unroll
  for (int off = 32; off >= 1; off >>= 1) {
#pragma unroll
    for (int m = 0; m < RP; ++m) {
      sa[m] += __shfl_xor(sa[m], off);
      sb[m] += __shfl_xor(sb[m], off);
    }
  }

  __shared__ float lsa[NW][RP], lsb[NW][RP];
  __shared__ double dmom[RP][NSC];
  if (lane == 0) {
#pragma unroll
    for (int m = 0; m < RP; ++m) { lsa[wv][m] = sa[m]; lsb[wv][m] = sb[m]; }
  }
  __syncthreads();
  if (threadIdx.x < RP) {
    const int m = threadIdx.x;
    const double rowA = (double)lsa[0][m] + lsa[1][m] + lsa[2][m] + lsa[3][m];
    const double rowB = (double)lsb[0][m] + lsb[1][m] + lsb[2][m] + lsb[3][m];
    const double avA = rowA * (1.0 / NN);
    const double avB = rowB * (1.0 / NN);
    avga[i0 + m] = (float)avA;
    avgb[i0 + m] = (float)avB;
    const double wi = (double)w[i0 + m];
    const double aiv = (double)a[i0 + m];
    const double biv = (double)b[i0 + m];
    dmom[m][0] = wi;
    dmom[m][1] = wi * aiv;
    dmom[m][2] = wi * aiv * aiv;
    dmom[m][3] = wi * biv;
    dmom[m][4] = wi * biv * biv;
    dmom[m][5] = wi * avA;
    dmom[m][6] = wi * avA * avA;
    dmom[m][7] = wi * avB;
    dmom[m][8] = wi * avB * avB;
  }
  __syncthreads();
  if (threadIdx.x == 0) {
#pragma unroll
    for (int t = 0; t < NSC; ++t) {
      double s = 0.0;
#pragma unroll
      for (int m = 0; m < RP; ++m) s += dmom[m][t];
      gmom[t * GBLK + blockIdx.x] = s;
    }
  }
}

// ---- K2: pass 2 — prologue scalars; 5-op Q' sweep (on-the-fly wr_j, s_j);
//      in-block T_AB finish -> fAB[1024]
__global__ __launch_bounds__(BLK) void k_pass2(
    const float* __restrict__ a, const float* __restrict__ b,
    const float* __restrict__ w,
    const float* __restrict__ avga, const float* __restrict__ avgb,
    const double* __restrict__ gmom,
    double* __restrict__ fAB) {
  const int lane = threadIdx.x & 63;
  const int wv = threadIdx.x >> 6;
  const int i0 = blockIdx.x * RP;

  // ---- prologue: W, Sua1, Sub1 -> ha, hb, Swr, Sws (all threads)
  double pW = 0.0, pU = 0.0, pV = 0.0;
#pragma unroll
  for (int k = 0; k < GBLK / BLK; ++k) {
    const int t = threadIdx.x + k * BLK;
    pW += gmom[0 * GBLK + t];
    pU += gmom[5 * GBLK + t];
    pV += gmom[7 * GBLK + t];
  }
#pragma unroll
  for (int off = 32; off >= 1; off >>= 1) {
    pW += __shfl_xor(pW, off);
    pU += __shfl_xor(pU, off);
    pV += __shfl_xor(pV, off);
  }
  __shared__ double l3[3][NW];
  if (lane == 0) { l3[0][wv] = pW; l3[1][wv] = pU; l3[2][wv] = pV; }
  __syncthreads();
  const double Wd   = l3[0][0] + l3[0][1] + l3[0][2] + l3[0][3];
  const double Sua1 = l3[1][0] + l3[1][1] + l3[1][2] + l3[1][3];
  const double Sub1 = l3[2][0] + l3[2][1] + l3[2][2] + l3[2][3];
  const double had = Sua1 / (2.0 * NN);   // ha = ga/(2N^2), ga = N*Sua1
  const double hbd = Sub1 / (2.0 * NN);
  const double Swrd = Sua1 - had * Wd;
  const double Swsd = Sub1 - hbd * Wd;
  const float ha = (float)had, hb = (float)hbd;

  float ai[RP], bi[RP], q[RP];
#pragma unroll
  for (int m = 0; m < RP; ++m) {
    ai[m] = a[i0 + m]; bi[m] = b[i0 + m];
    q[m] = 0.f;
  }

  const int jb = wv * SEGC;
  const float4* a4 = (const float4*)(a + jb)    + lane;
  const float4* b4 = (const float4*)(b + jb)    + lane;
  const float4* w4 = (const float4*)(w + jb)    + lane;
  const float4* c4 = (const float4*)(avga + jb) + lane;
  const float4* d4 = (const float4*)(avgb + jb) + lane;

#pragma unroll 1
  for (int k = 0; k < ITERS; ++k) {
    const int ix = k * 64;
    const float4 A = a4[ix], B = b4[ix], Wt = w4[ix], CA = c4[ix], CB = d4[ix];
#define P2E(e)                                                  \
    {                                                           \
      const float wrj = Wt.e * (CA.e - ha);                     \
      const float sj  = CB.e - hb;                              \
      _Pragma("unroll")                                         \
      for (int m = 0; m < RP; ++m) {                            \
        const float ta = ai[m] - A.e;                           \
        const float tb = bi[m] - B.e;                           \
        const float wdp = fmaf(Wt.e, fabsf(ta), -wrj);          \
        const float ep = fabsf(tb) - sj;                        \
        q[m] = fmaf(wdp, ep, q[m]);                             \
      }                                                         \
    }
    P2E(x) P2E(y) P2E(z) P2E(w)
#undef P2E
  }

#pragma unroll
  for (int off = 32; off >= 1; off >>= 1) {
#pragma unroll
    for (int m = 0; m < RP; ++m) q[m] += __shfl_xor(q[m], off);
  }

  __shared__ float lq[NW][RP];
  __shared__ double lab[RP];
  if (lane == 0) {
#pragma unroll
    for (int m = 0; m < RP; ++m) lq[wv][m] = q[m];
  }
  __syncthreads();
  if (threadIdx.x < RP) {
    const int m = threadIdx.x;
    const double Qi = (double)lq[0][m] + lq[1][m] + lq[2][m] + lq[3][m];
    const double avA = (double)avga[i0 + m];
    const double avB = (double)avgb[i0 + m];
    const double ri = avA - had;
    const double si = avB - hbd;
    const double wi = (double)w[i0 + m];
    const double P0a = avA * (double)NN;
    const double P0b = avB * (double)NN;
    const double TAB = Qi - si * (P0a - Swrd) - ri * (P0b - Swsd) + ri * si * Wd;
    lab[m] = fabs(TAB) * wi;
  }
  __syncthreads();
  if (threadIdx.x == 0) {
    double s = 0.0;
#pragma unroll
    for (int m = 0; m < RP; ++m) s += lab[m];
    fAB[blockIdx.x] = s;
  }
}

// ---------- K3: finalize — reduce fAB + 9 moments; closed-form dens; power
__global__ __launch_bounds__(BLK) void k_fin(
    const double* __restrict__ fAB, const double* __restrict__ gmom,
    const int* __restrict__ powerPtr, float* __restrict__ out) {
  const int lane = threadIdx.x & 63;
  const int wv = threadIdx.x >> 6;

  double ab = 0.0;
#pragma unroll
  for (int k = 0; k < GBLK / BLK; ++k) ab += fAB[threadIdx.x + k * BLK];
  double p[NSC];
#pragma unroll
  for (int t = 0; t < NSC; ++t) {
    double s = 0.0;
#pragma unroll
    for (int k = 0; k < GBLK / BLK; ++k) s += gmom[t * GBLK + threadIdx.x + k * BLK];
    p[t] = s;
  }
#pragma unroll
  for (int off = 32; off >= 1; off >>= 1) {
    ab += __shfl_xor(ab, off);
#pragma unroll
    for (int t = 0; t < NSC; ++t) p[t] += __shfl_xor(p[t], off);
  }
  __shared__ double l[NW];
  __shared__ double lp[NSC][NW];
  if (lane == 0) {
    l[wv] = ab;
#pragma unroll
    for (int t = 0; t < NSC; ++t) lp[t][wv] = p[t];
  }
  __syncthreads();

  if (threadIdx.x == 0) {
    const double n2 = (double)NN * (double)NN;
    const double sab = l[0] + l[1] + l[2] + l[3];
    double sc[NSC];
#pragma unroll
    for (int t = 0; t < NSC; ++t) sc[t] = lp[t][0] + lp[t][1] + lp[t][2] + lp[t][3];
    const double W = sc[0], Ma1 = sc[1], Ma2 = sc[2], Mb1 = sc[3], Mb2 = sc[4];
    const double Sua1 = sc[5], Sua2 = sc[6], Sub1 = sc[7], Sub2 = sc[8];
    const double ha = Sua1 / (2.0 * NN);
    const double hb = Sub1 / (2.0 * NN);
    const double Swr  = Sua1 - ha * W;
    const double Sws  = Sub1 - hb * W;
    const double Swr2 = Sua2 - 2.0 * ha * Sua1 + ha * ha * W;
    const double Sws2 = Sub2 - 2.0 * hb * Sub1 + hb * hb * W;

    const double S_AA = 2.0 * W * Ma2 - 2.0 * Ma1 * Ma1
                      - 4.0 * (double)NN * (Swr2 + ha * Swr)
                      + 2.0 * W * Swr2 + 2.0 * Swr * Swr;
    const double S_BB = 2.0 * W * Mb2 - 2.0 * Mb1 * Mb1
                      - 4.0 * (double)NN * (Sws2 + hb * Sws)
                      + 2.0 * W * Sws2 + 2.0 * Sws * Sws;

    const double num = sab / n2;
    const double mAA = S_AA / n2;
    const double mBB = S_BB / n2;
    const double den = fabs(mAA * mBB);
    const int pw = powerPtr[0];
    double d;
    if (pw == 1) {
      d = num / sqrt(den + 1e-12);
    } else if (pw == 2) {
      d = (num * num) / (den + 1e-12);
    } else {
      d = pow(num / sqrt(mAA * mBB) + 1e-12, (double)pw);
    }
    if (isnan(d)) d = 0.0;
    if (d < 0.0) d = 0.0;
    out[0] = (float)d;
  }
}

// -------------------------------------------------------------------- launcher
extern "C" void kernel_launch(void* const* d_in, const int* in_sizes, int n_in,
                              void* d_out, int out_size, void* d_ws, size_t ws_size,
                              hipStream_t stream) {
  const float* a = (const float*)d_in[0];
  const float* b = (const float*)d_in[1];
  const float* w = (const float*)d_in[2];
  const int* power = (const int*)d_in[3];
  float* out = (float*)d_out;

  double* dws = (double*)d_ws;           // 8B-aligned base
  double* gmom = dws;                    // [9*1024]
  double* fAB  = gmom + NSC * GBLK;      // [1024]
  float* fp    = (float*)(fAB + GBLK);
  float* avga  = fp;                     // [N]
  float* avgb  = avga + NN;              // [N]

  k_pass1<<<GBLK, BLK, 0, stream>>>(a, b, w, avga, avgb, gmom);
  k_pass2<<<GBLK, BLK, 0, stream>>>(a, b, w, avga, avgb, gmom, fAB);
  k_fin<<<1, BLK, 0, stream>>>(fAB, gmom, power, out);
}

// Round 17
// 35.328 us; speedup vs baseline: 1.1237x; 1.0262x over previous
//
#include <hip/hip_runtime.h>
#include <math.h>

// DisCo (distance correlation) for N=8192, scalar output. THREE dispatches.
// R17 = R16 structure with pass2 at RPT=16 (512 blocks): halves pass2's L2
// read traffic (164->82 MB) and doubles VALU per loaded byte; 2 waves/SIMD
// grid-limited, covered by 16 indep FMA chains/lane (ILP-for-TLP, cf. R15).
// Algebra (validated R11/R13/R15/R16, absmax 0.0):
//   ha = Sua1/(2N) (Sua1 = sum w_i avga_i); r_i = avga_i - ha
//   Q'_i = sum_j w_j (|a_i-a_j| - r_j)(|b_i-b_j| - s_j)   (5 VALU/pair)
//   T_AB_i = Q'_i - s_i(P0a_i-Swr) - r_i(P0b_i-Sws) + r_i s_i W
//   S_AA = 2W*Ma2 - 2Ma1^2 - 4N(Swr2 + ha*Swr) + 2W*Swr2 + 2Swr^2 (closed)
//   K1 k_pass1 (1024): 8 full rows/block; avg + 9 ha-free moment partials.
//   K2 k_pass2 (512):  16 full rows/block; prologue scalars; 5-op Q' sweep
//       with on-the-fly wr_j,s_j; in-block T_AB -> fAB[512].
//   K3 k_fin   (1x256): reduce fAB + moments; closed-form dens; power; clamp.
// No atomics/fences (R4). Fixed-order reductions -> deterministic.
// Ledger: R4 no per-block fences; R6 VGPR cliff; R9 epilogue<<main, 1-block
// reads <<100KB; R10 no redundant per-block O(N) rebuilds; R12 serial merge
// loses to gap; R14 packed-f32 neutral; R15/R17 ILP-for-TLP.

#define NN 8192
#define BLK 256
#define NW 4                      // waves per block
#define RP 8                      // pass1 rows per block
#define GBLK (NN / RP)            // 1024 pass1 blocks
#define RP2 16                    // pass2 rows per block
#define G2BLK (NN / RP2)          // 512 pass2 blocks
#define SEGC (NN / NW)            // 2048 cols per wave
#define ITERS (SEGC / 256)        // 8 float4-iters per wave
#define NSC 9   // 0:W 1:Ma1 2:Ma2 3:Mb1 4:Mb2 5:Sua1 6:Sua2 7:Sub1 8:Sub2

// ------------------------- K1: pass 1 — full rows, avg + ha-free moments
__global__ __launch_bounds__(BLK) void k_pass1(
    const float* __restrict__ a, const float* __restrict__ b,
    const float* __restrict__ w,
    float* __restrict__ avga, float* __restrict__ avgb,
    double* __restrict__ gmom) {
  const int lane = threadIdx.x & 63;
  const int wv = threadIdx.x >> 6;
  const int i0 = blockIdx.x * RP;

  float ai[RP], bi[RP], sa[RP], sb[RP];
#pragma unroll
  for (int m = 0; m < RP; ++m) {
    ai[m] = a[i0 + m]; bi[m] = b[i0 + m];
    sa[m] = 0.f; sb[m] = 0.f;
  }

  const int jb = wv * SEGC;
  const float4* a4 = (const float4*)(a + jb) + lane;
  const float4* b4 = (const float4*)(b + jb) + lane;
  const float4* w4 = (const float4*)(w + jb) + lane;

#pragma unroll 1
  for (int k = 0; k < ITERS; ++k) {
    const int ix = k * 64;
    const float4 A = a4[ix], B = b4[ix], Wt = w4[ix];
#define P1E(e)                                              \
    {                                                       \
      _Pragma("unroll")                                     \
      for (int m = 0; m < RP; ++m) {                        \
        sa[m] = fmaf(fabsf(ai[m] - A.e), Wt.e, sa[m]);      \
        sb[m] = fmaf(fabsf(bi[m] - B.e), Wt.e, sb[m]);      \
      }                                                     \
    }
    P1E(x) P1E(y) P1E(z) P1E(w)
#undef P1E
  }

#pragma unroll
  for (int off = 32; off >= 1; off >>= 1) {
#pragma unroll
    for (int m = 0; m < RP; ++m) {
      sa[m] += __shfl_xor(sa[m], off);
      sb[m] += __shfl_xor(sb[m], off);
    }
  }

  __shared__ float lsa[NW][RP], lsb[NW][RP];
  __shared__ double dmom[RP][NSC];
  if (lane == 0) {
#pragma unroll
    for (int m = 0; m < RP; ++m) { lsa[wv][m] = sa[m]; lsb[wv][m] = sb[m]; }
  }
  __syncthreads();
  if (threadIdx.x < RP) {
    const int m = threadIdx.x;
    const double rowA = (double)lsa[0][m] + lsa[1][m] + lsa[2][m] + lsa[3][m];
    const double rowB = (double)lsb[0][m] + lsb[1][m] + lsb[2][m] + lsb[3][m];
    const double avA = rowA * (1.0 / NN);
    const double avB = rowB * (1.0 / NN);
    avga[i0 + m] = (float)avA;
    avgb[i0 + m] = (float)avB;
    const double wi = (double)w[i0 + m];
    const double aiv = (double)a[i0 + m];
    const double biv = (double)b[i0 + m];
    dmom[m][0] = wi;
    dmom[m][1] = wi * aiv;
    dmom[m][2] = wi * aiv * aiv;
    dmom[m][3] = wi * biv;
    dmom[m][4] = wi * biv * biv;
    dmom[m][5] = wi * avA;
    dmom[m][6] = wi * avA * avA;
    dmom[m][7] = wi * avB;
    dmom[m][8] = wi * avB * avB;
  }
  __syncthreads();
  if (threadIdx.x == 0) {
#pragma unroll
    for (int t = 0; t < NSC; ++t) {
      double s = 0.0;
#pragma unroll
      for (int m = 0; m < RP; ++m) s += dmom[m][t];
      gmom[t * GBLK + blockIdx.x] = s;
    }
  }
}

// ---- K2: pass 2 — 16 full rows/block; prologue scalars; 5-op Q' sweep;
//      in-block T_AB finish -> fAB[512]
__global__ __launch_bounds__(BLK) void k_pass2(
    const float* __restrict__ a, const float* __restrict__ b,
    const float* __restrict__ w,
    const float* __restrict__ avga, const float* __restrict__ avgb,
    const double* __restrict__ gmom,
    double* __restrict__ fAB) {
  const int lane = threadIdx.x & 63;
  const int wv = threadIdx.x >> 6;
  const int i0 = blockIdx.x * RP2;

  // ---- prologue: W, Sua1, Sub1 -> ha, hb, Swr, Sws (all threads)
  double pW = 0.0, pU = 0.0, pV = 0.0;
#pragma unroll
  for (int k = 0; k < GBLK / BLK; ++k) {
    const int t = threadIdx.x + k * BLK;
    pW += gmom[0 * GBLK + t];
    pU += gmom[5 * GBLK + t];
    pV += gmom[7 * GBLK + t];
  }
#pragma unroll
  for (int off = 32; off >= 1; off >>= 1) {
    pW += __shfl_xor(pW, off);
    pU += __shfl_xor(pU, off);
    pV += __shfl_xor(pV, off);
  }
  __shared__ double l3[3][NW];
  if (lane == 0) { l3[0][wv] = pW; l3[1][wv] = pU; l3[2][wv] = pV; }
  __syncthreads();
  const double Wd   = l3[0][0] + l3[0][1] + l3[0][2] + l3[0][3];
  const double Sua1 = l3[1][0] + l3[1][1] + l3[1][2] + l3[1][3];
  const double Sub1 = l3[2][0] + l3[2][1] + l3[2][2] + l3[2][3];
  const double had = Sua1 / (2.0 * NN);
  const double hbd = Sub1 / (2.0 * NN);
  const double Swrd = Sua1 - had * Wd;
  const double Swsd = Sub1 - hbd * Wd;
  const float ha = (float)had, hb = (float)hbd;

  float ai[RP2], bi[RP2], q[RP2];
#pragma unroll
  for (int m = 0; m < RP2; ++m) {
    ai[m] = a[i0 + m]; bi[m] = b[i0 + m];
    q[m] = 0.f;
  }

  const int jb = wv * SEGC;
  const float4* a4 = (const float4*)(a + jb)    + lane;
  const float4* b4 = (const float4*)(b + jb)    + lane;
  const float4* w4 = (const float4*)(w + jb)    + lane;
  const float4* c4 = (const float4*)(avga + jb) + lane;
  const float4* d4 = (const float4*)(avgb + jb) + lane;

#pragma unroll 1
  for (int k = 0; k < ITERS; ++k) {
    const int ix = k * 64;
    const float4 A = a4[ix], B = b4[ix], Wt = w4[ix], CA = c4[ix], CB = d4[ix];
#define P2E(e)                                                  \
    {                                                           \
      const float wrj = Wt.e * (CA.e - ha);                     \
      const float sj  = CB.e - hb;                              \
      _Pragma("unroll")                                         \
      for (int m = 0; m < RP2; ++m) {                           \
        const float ta = ai[m] - A.e;                           \
        const float tb = bi[m] - B.e;                           \
        const float wdp = fmaf(Wt.e, fabsf(ta), -wrj);          \
        const float ep = fabsf(tb) - sj;                        \
        q[m] = fmaf(wdp, ep, q[m]);                             \
      }                                                         \
    }
    P2E(x) P2E(y) P2E(z) P2E(w)
#undef P2E
  }

#pragma unroll
  for (int off = 32; off >= 1; off >>= 1) {
#pragma unroll
    for (int m = 0; m < RP2; ++m) q[m] += __shfl_xor(q[m], off);
  }

  __shared__ float lq[NW][RP2];
  __shared__ double lab[RP2];
  if (lane == 0) {
#pragma unroll
    for (int m = 0; m < RP2; ++m) lq[wv][m] = q[m];
  }
  __syncthreads();
  if (threadIdx.x < RP2) {                    // lanes 0-15 of wave 0 hold Wd etc.
    const int m = threadIdx.x;
    const double Qi = (double)lq[0][m] + lq[1][m] + lq[2][m] + lq[3][m];
    const double avA = (double)avga[i0 + m];
    const double avB = (double)avgb[i0 + m];
    const double ri = avA - had;
    const double si = avB - hbd;
    const double wi = (double)w[i0 + m];
    const double P0a = avA * (double)NN;
    const double P0b = avB * (double)NN;
    const double TAB = Qi - si * (P0a - Swrd) - ri * (P0b - Swsd) + ri * si * Wd;
    lab[m] = fabs(TAB) * wi;
  }
  __syncthreads();
  if (threadIdx.x == 0) {
    double s = 0.0;
#pragma unroll
    for (int m = 0; m < RP2; ++m) s += lab[m];
    fAB[blockIdx.x] = s;
  }
}

// ---------- K3: finalize — reduce fAB + 9 moments; closed-form dens; power
__global__ __launch_bounds__(BLK) void k_fin(
    const double* __restrict__ fAB, const double* __restrict__ gmom,
    const int* __restrict__ powerPtr, float* __restrict__ out) {
  const int lane = threadIdx.x & 63;
  const int wv = threadIdx.x >> 6;

  double ab = 0.0;
#pragma unroll
  for (int k = 0; k < G2BLK / BLK; ++k) ab += fAB[threadIdx.x + k * BLK];
  double p[NSC];
#pragma unroll
  for (int t = 0; t < NSC; ++t) {
    double s = 0.0;
#pragma unroll
    for (int k = 0; k < GBLK / BLK; ++k) s += gmom[t * GBLK + threadIdx.x + k * BLK];
    p[t] = s;
  }
#pragma unroll
  for (int off = 32; off >= 1; off >>= 1) {
    ab += __shfl_xor(ab, off);
#pragma unroll
    for (int t = 0; t < NSC; ++t) p[t] += __shfl_xor(p[t], off);
  }
  __shared__ double l[NW];
  __shared__ double lp[NSC][NW];
  if (lane == 0) {
    l[wv] = ab;
#pragma unroll
    for (int t = 0; t < NSC; ++t) lp[t][wv] = p[t];
  }
  __syncthreads();

  if (threadIdx.x == 0) {
    const double n2 = (double)NN * (double)NN;
    const double sab = l[0] + l[1] + l[2] + l[3];
    double sc[NSC];
#pragma unroll
    for (int t = 0; t < NSC; ++t) sc[t] = lp[t][0] + lp[t][1] + lp[t][2] + lp[t][3];
    const double W = sc[0], Ma1 = sc[1], Ma2 = sc[2], Mb1 = sc[3], Mb2 = sc[4];
    const double Sua1 = sc[5], Sua2 = sc[6], Sub1 = sc[7], Sub2 = sc[8];
    const double ha = Sua1 / (2.0 * NN);
    const double hb = Sub1 / (2.0 * NN);
    const double Swr  = Sua1 - ha * W;
    const double Sws  = Sub1 - hb * W;
    const double Swr2 = Sua2 - 2.0 * ha * Sua1 + ha * ha * W;
    const double Sws2 = Sub2 - 2.0 * hb * Sub1 + hb * hb * W;

    const double S_AA = 2.0 * W * Ma2 - 2.0 * Ma1 * Ma1
                      - 4.0 * (double)NN * (Swr2 + ha * Swr)
                      + 2.0 * W * Swr2 + 2.0 * Swr * Swr;
    const double S_BB = 2.0 * W * Mb2 - 2.0 * Mb1 * Mb1
                      - 4.0 * (double)NN * (Sws2 + hb * Sws)
                      + 2.0 * W * Sws2 + 2.0 * Sws * Sws;

    const double num = sab / n2;
    const double mAA = S_AA / n2;
    const double mBB = S_BB / n2;
    const double den = fabs(mAA * mBB);
    const int pw = powerPtr[0];
    double d;
    if (pw == 1) {
      d = num / sqrt(den + 1e-12);
    } else if (pw == 2) {
      d = (num * num) / (den + 1e-12);
    } else {
      d = pow(num / sqrt(mAA * mBB) + 1e-12, (double)pw);
    }
    if (isnan(d)) d = 0.0;
    if (d < 0.0) d = 0.0;
    out[0] = (float)d;
  }
}

// -------------------------------------------------------------------- launcher
extern "C" void kernel_launch(void* const* d_in, const int* in_sizes, int n_in,
                              void* d_out, int out_size, void* d_ws, size_t ws_size,
                              hipStream_t stream) {
  const float* a = (const float*)d_in[0];
  const float* b = (const float*)d_in[1];
  const float* w = (const float*)d_in[2];
  const int* power = (const int*)d_in[3];
  float* out = (float*)d_out;

  double* dws = (double*)d_ws;           // 8B-aligned base
  double* gmom = dws;                    // [9*1024]
  double* fAB  = gmom + NSC * GBLK;      // [512]
  float* fp    = (float*)(fAB + G2BLK);
  float* avga  = fp;                     // [N]
  float* avgb  = avga + NN;              // [N]

  k_pass1<<<GBLK, BLK, 0, stream>>>(a, b, w, avga, avgb, gmom);
  k_pass2<<<G2BLK, BLK, 0, stream>>>(a, b, w, avga, avgb, gmom, fAB);
  k_fin<<<1, BLK, 0, stream>>>(fAB, gmom, power, out);
}